// Round 8
// baseline (318.289 us; speedup 1.0000x reference)
//
#include <hip/hip_runtime.h>
#include <math.h>

#define N 8192
#define D 256
#define EPSF 1e-8f
#define NJS 4            // j-splits
#define ROWS 32          // out-rows per block
#define JSPAN 2048       // j-cols per block
#define NU 64            // units per block: 16 chunks x 4 K-slices

// ws float offsets
#define WS_SQ    0
#define WS_RINV  (N)
#define WS_GMEAN (2*N)
#define WS_MAXN  (2*N+256)
#define WS_COLP  (2*N+512)              // [65536]
#define WS_P0    (2*N+512+65536)        // deg[4N] pot[4N] sl[4N] st[4N] tv[20N] = 36N
#define WS_TIX   (WS_P0+36*N)           // [20N] ints
#define WS_EBF   (WS_TIX+20*N)          // [2M ushort] bf16 emb (4MB)

typedef __attribute__((ext_vector_type(8))) short bf16x8;
typedef __attribute__((ext_vector_type(4))) float f32x4;

__device__ __forceinline__ unsigned short f2bf(float f) {
    unsigned u = __float_as_uint(f);
    u += 0x7fffu + ((u >> 16) & 1u);
    return (unsigned short)(u >> 16);
}

#define INS5(TV, TI, dpv, jv) do {                                              \
    if ((dpv) < (TV)[4]) {                                                      \
      bool _b3 = (dpv) < (TV)[3], _b2 = (dpv) < (TV)[2];                        \
      bool _b1 = (dpv) < (TV)[1], _b0 = (dpv) < (TV)[0];                        \
      (TV)[4] = _b3 ? (TV)[3] : (dpv); (TI)[4] = _b3 ? (TI)[3] : (jv);          \
      (TV)[3] = _b3 ? (_b2 ? (TV)[2] : (dpv)) : (TV)[3];                        \
      (TI)[3] = _b3 ? (_b2 ? (TI)[2] : (jv))  : (TI)[3];                        \
      (TV)[2] = _b2 ? (_b1 ? (TV)[1] : (dpv)) : (TV)[2];                        \
      (TI)[2] = _b2 ? (_b1 ? (TI)[1] : (jv))  : (TI)[2];                        \
      (TV)[1] = _b1 ? (_b0 ? (TV)[0] : (dpv)) : (TV)[1];                        \
      (TI)[1] = _b1 ? (_b0 ? (TI)[0] : (jv))  : (TI)[1];                        \
      (TV)[0] = _b0 ? (dpv) : (TV)[0]; (TI)[0] = _b0 ? (jv) : (TI)[0];          \
    }                                                                           \
  } while (0)

__global__ void k_prep(const float* __restrict__ emb, float* __restrict__ ws,
                       unsigned short* __restrict__ ebf) {
    if (blockIdx.x < 2048) {
        int row = blockIdx.x * 4 + (threadIdx.x >> 6);
        int lane = threadIdx.x & 63;
        float4 v = *(const float4*)(emb + (size_t)row * D + lane * 4);
        ushort4 b;
        b.x = f2bf(v.x); b.y = f2bf(v.y); b.z = f2bf(v.z); b.w = f2bf(v.w);
        *(ushort4*)(ebf + (size_t)row * D + lane * 4) = b;
        float s = v.x * v.x + v.y * v.y + v.z * v.z + v.w * v.w;
#pragma unroll
        for (int mk = 32; mk >= 1; mk >>= 1) s += __shfl_xor(s, mk);
        if (lane == 0) {
            ws[WS_SQ + row] = s;
            float nrm = sqrtf(s);
            ws[WS_RINV + row] = 1.0f / fmaxf(nrm, 1e-12f);
            atomicMax((unsigned*)(ws + WS_MAXN), __float_as_uint(nrm));
        }
    } else {
        int d = threadIdx.x;
        int b = blockIdx.x - 2048;
        float s = 0.f;
        for (int r = b * 32; r < b * 32 + 32; ++r) s += emb[(size_t)r * D + d];
        ws[WS_COLP + b * 256 + d] = s;
    }
}

__global__ void k_colred(float* __restrict__ ws) {
    int d = threadIdx.x;
    float s = 0.f;
    for (int b = 0; b < 256; ++b) s += ws[WS_COLP + b * 256 + d];
    ws[WS_GMEAN + d] = s * (1.0f / N);
}

// Stage [128 j][64 K] bf16 tile (16KB) cooperatively: wave w stages rows
// w*32+q*8.. via global_load_lds (linear LDS dest, PRE-SWIZZLED global src).
// Swizzle: stored[row][pg] = logical[row][pg ^ (row&7)] (16B groups).
#define STAGE(BUF, U) do {                                                      \
    const int _cc = (U) >> 2, _k0 = ((U) & 3) << 6;                             \
    const size_t _rb = (size_t)(j0 + _cc * 128 + (w << 5) + srow) * D + _k0 + (sc << 3); \
    _Pragma("unroll")                                                           \
    for (int q = 0; q < 4; ++q) {                                               \
      __builtin_amdgcn_global_load_lds(                                         \
        (const __attribute__((address_space(1))) void*)(ebf + _rb + (size_t)(q << 3) * D), \
        (__attribute__((address_space(3))) void*)&tile[BUF][((w << 5) + (q << 3)) * 64], \
        16, 0, 0);                                                              \
    } } while (0)

// Block = 32 out-rows x 2048 j. 4 waves share out-rows (bfr identical), split
// each 128-j chunk into 32-j quadrants. LDS double-buffered A-tiles; adj
// register-prefetched 3 units ahead (h==0 -> h==3); sq/rv 2 ahead.
// NOTE: no min-occupancy in launch_bounds -- R7's (256,3) forced VGPR=84 and
// ~3x VALU inflation (AGPR/scratch shuffling). Let VGPRs float.
__global__ __launch_bounds__(256) void k_main(
    const float* __restrict__ adj,
    const unsigned short* __restrict__ ebf,
    const float* __restrict__ ws,
    float* __restrict__ pout,
    int* __restrict__ tixp)
{
    __shared__ unsigned short tile[2][128 * 64];   // 2 x 16KB

    const int tid = threadIdx.x;
    const int w = tid >> 6;
    const int l = tid & 63;
    const int lid = l & 15;
    const int g = l >> 4;
    const int srow = l >> 3;              // staging: row-in-slab 0..7
    const int sc = (l & 7) ^ srow;        // staging: pre-swizzled 16B group
    const int panel = blockIdx.x >> 2;    // 256 panels
    const int js = blockIdx.x & 3;
    const int row0 = panel * ROWS;
    const int j0 = js * JSPAN;

    const float* sq = ws + WS_SQ;
    const float* rinv = ws + WS_RINV;

    // persistent out-row fragments (same for all waves)
    bf16x8 bfr[2][8];
    float rvr[2];
    int r_[2];
#pragma unroll
    for (int nf = 0; nf < 2; ++nf) {
        int r = row0 + nf * 16 + lid;
        r_[nf] = r;
        rvr[nf] = rinv[r];
#pragma unroll
        for (int ks = 0; ks < 8; ++ks)
            bfr[nf][ks] = *(const bf16x8*)(ebf + (size_t)r * D + ks * 32 + g * 8);
    }

    float deg[2] = {0.f, 0.f}, pot[2] = {0.f, 0.f};
    float sl[2] = {0.f, 0.f}, st[2] = {0.f, 0.f};
    float tv[2][5]; int tix[2][5];
#pragma unroll
    for (int nf = 0; nf < 2; ++nf)
#pragma unroll
        for (int s2 = 0; s2 < 5; ++s2) { tv[nf][s2] = 1e30f; tix[nf][s2] = N; }

    f32x4 acc[2][2];
#pragma unroll
    for (int nf = 0; nf < 2; ++nf)
#pragma unroll
        for (int mf = 0; mf < 2; ++mf) acc[nf][mf] = (f32x4){0.f, 0.f, 0.f, 0.f};
    f32x4 advA[2][2], sqv[2], rvv[2];

    STAGE(0, 0);
    __syncthreads();

#pragma unroll 1
    for (int uu = 0; uu < NU; uu += 4) {
#pragma unroll
        for (int h = 0; h < 4; ++h) {
            const int u = uu + h;
            const int cur = u & 1;
            if (u + 1 < NU) STAGE(cur ^ 1, u + 1);
            if (h == 0) {
                // adj prefetch for this chunk's EPI (used at h==3): HBM, ~3-unit window
                const int jj = j0 + (uu >> 2) * 128 + (w << 5);
#pragma unroll
                for (int nf = 0; nf < 2; ++nf)
#pragma unroll
                    for (int mf = 0; mf < 2; ++mf)
                        advA[nf][mf] = __builtin_nontemporal_load(
                            (const f32x4*)(adj + (size_t)r_[nf] * N + jj + mf * 16 + g * 4));
            }
            if (h == 1) {
                // j-side stats (L2-hot), 2-unit window
                const int jj = j0 + (uu >> 2) * 128 + (w << 5);
#pragma unroll
                for (int mf = 0; mf < 2; ++mf) {
                    sqv[mf] = *(const f32x4*)(sq + jj + mf * 16 + g * 4);
                    rvv[mf] = *(const f32x4*)(rinv + jj + mf * 16 + g * 4);
                }
            }
            // compute unit u: 2 K-sub-slices of 32, 8 MFMAs
#pragma unroll
            for (int ksl = 0; ksl < 2; ++ksl) {
                const int pg = ((ksl << 2) + g) ^ (lid & 7);
                bf16x8 afr[2];
#pragma unroll
                for (int mf = 0; mf < 2; ++mf)
                    afr[mf] = *(const bf16x8*)&tile[cur][((w << 5) + (mf << 4) + lid) * 64 + (pg << 3)];
#pragma unroll
                for (int nf = 0; nf < 2; ++nf)
#pragma unroll
                    for (int mf = 0; mf < 2; ++mf)
                        acc[nf][mf] = __builtin_amdgcn_mfma_f32_16x16x32_bf16(
                            afr[mf], bfr[nf][h * 2 + ksl], acc[nf][mf], 0, 0, 0);
            }
            if (h == 3) {
                const int jj = j0 + (uu >> 2) * 128 + (w << 5);
#pragma unroll
                for (int nf = 0; nf < 2; ++nf) {
#pragma unroll
                    for (int mf = 0; mf < 2; ++mf) {
#pragma unroll
                        for (int e = 0; e < 4; ++e) {
                            const float gv = acc[nf][mf][e];
                            const float a = advA[nf][mf][e];
                            const int j = jj + mf * 16 + g * 4 + e;
                            deg[nf] += a;
                            pot[nf] = fmaf(a, gv, pot[nf]);
                            const float s = (gv * rvr[nf]) * (rvv[mf][e] * a);
                            const float ex = __expf(s);
                            sl[nf] += ex;
                            st[nf] = fmaf(ex, s, st[nf]);
                            float dp = fmaf(-2.f, gv, sqv[mf][e]);
                            dp = (j == r_[nf]) ? 1e30f : dp;
                            INS5(tv[nf], tix[nf], dp, j);
                        }
                        acc[nf][mf] = (f32x4){0.f, 0.f, 0.f, 0.f};
                    }
                }
            }
            __syncthreads();
        }
    }

    // reduce across g-lanes (xor 16, 32) sharing each out-row
#pragma unroll
    for (int nf = 0; nf < 2; ++nf) {
#pragma unroll
        for (int mk = 16; mk <= 32; mk <<= 1) {
            deg[nf] += __shfl_xor(deg[nf], mk);
            pot[nf] += __shfl_xor(pot[nf], mk);
            sl[nf] += __shfl_xor(sl[nf], mk);
            st[nf] += __shfl_xor(st[nf], mk);
            float od[5]; int oi[5];
#pragma unroll
            for (int s2 = 0; s2 < 5; ++s2) {
                od[s2] = __shfl_xor(tv[nf][s2], mk);
                oi[s2] = __shfl_xor(tix[nf][s2], mk);
            }
#pragma unroll
            for (int s2 = 0; s2 < 5; ++s2) INS5(tv[nf], tix[nf], od[s2], oi[s2]);
        }
    }

    // cross-wave merge via LDS (overlay on tile memory; tile no longer read)
    float* lds_s  = (float*)&tile[0][0];           // [4][32][4]
    float* lds_tv = lds_s + 4 * 32 * 4;            // [4][32][5]
    int*   lds_ti = (int*)(lds_tv + 4 * 32 * 5);   // [4][32][5]
#pragma unroll
    for (int nf = 0; nf < 2; ++nf) {
        if (g == 0) {
            int lr = nf * 16 + lid;
            lds_s[(w * 32 + lr) * 4 + 0] = deg[nf];
            lds_s[(w * 32 + lr) * 4 + 1] = pot[nf];
            lds_s[(w * 32 + lr) * 4 + 2] = sl[nf];
            lds_s[(w * 32 + lr) * 4 + 3] = st[nf];
#pragma unroll
            for (int s2 = 0; s2 < 5; ++s2) {
                lds_tv[(w * 32 + lr) * 5 + s2] = tv[nf][s2];
                lds_ti[(w * 32 + lr) * 5 + s2] = tix[nf][s2];
            }
        }
    }
    __syncthreads();

    if (tid < 32) {
        float dg = 0.f, pt = 0.f, ll = 0.f, tt = 0.f;
#pragma unroll
        for (int w2 = 0; w2 < 4; ++w2) {
            dg += lds_s[(w2 * 32 + tid) * 4 + 0];
            pt += lds_s[(w2 * 32 + tid) * 4 + 1];
            ll += lds_s[(w2 * 32 + tid) * 4 + 2];
            tt += lds_s[(w2 * 32 + tid) * 4 + 3];
        }
        float mtv[5]; int mti[5];
#pragma unroll
        for (int s2 = 0; s2 < 5; ++s2) {
            mtv[s2] = lds_tv[tid * 5 + s2];
            mti[s2] = lds_ti[tid * 5 + s2];
        }
#pragma unroll
        for (int w2 = 1; w2 < 4; ++w2)
#pragma unroll
            for (int s2 = 0; s2 < 5; ++s2)
                INS5(mtv, mti, lds_tv[(w2 * 32 + tid) * 5 + s2], lds_ti[(w2 * 32 + tid) * 5 + s2]);
        const int slot = js * N + row0 + tid;
        pout[slot] = dg;
        pout[4 * N + slot] = pt;
        pout[8 * N + slot] = ll;
        pout[12 * N + slot] = tt;
#pragma unroll
        for (int s2 = 0; s2 < 5; ++s2) {
            pout[16 * N + slot * 5 + s2] = mtv[s2];
            tixp[slot * 5 + s2] = mti[s2];
        }
    }
}

__global__ void k_final(const float* __restrict__ emb, const float* __restrict__ ws,
                        const int* __restrict__ tixp, float* __restrict__ out) {
    int row = blockIdx.x * 4 + (threadIdx.x >> 6);
    int lane = threadIdx.x & 63;
    const float* p0 = ws + WS_P0;

    float dg = 0.f, pt = 0.f, ll = 0.f, tt = 0.f;
#pragma unroll
    for (int js = 0; js < NJS; ++js) {
        int slot = js * N + row;
        dg += p0[slot]; pt += p0[4 * N + slot];
        ll += p0[8 * N + slot]; tt += p0[12 * N + slot];
    }

    float cd[20]; int ci[20];
#pragma unroll
    for (int js = 0; js < NJS; ++js)
#pragma unroll
        for (int s = 0; s < 5; ++s) {
            int slot = js * N + row;
            cd[js * 5 + s] = p0[16 * N + slot * 5 + s];
            ci[js * 5 + s] = tixp[slot * 5 + s];
        }
    int nb[5];
    unsigned picked = 0;
#pragma unroll
    for (int sel = 0; sel < 5; ++sel) {
        float best = 1e31f; int bi = 0, bq = 0;
#pragma unroll
        for (int q = 0; q < 20; ++q) {
            bool ok = (((picked >> q) & 1u) == 0u) && (cd[q] < best);
            best = ok ? cd[q] : best;
            bi = ok ? ci[q] : bi;
            bq = ok ? q : bq;
        }
        picked |= (1u << bq);
        nb[sel] = bi;
    }

    float4 e = *(const float4*)(emb + (size_t)row * D + lane * 4);
    float4 gm = *(const float4*)(ws + WS_GMEAN + lane * 4);
    float gx = e.x - gm.x, gy = e.y - gm.y, gz = e.z - gm.z, gw = e.w - gm.w;
    float gd = gx * gx + gy * gy + gz * gz + gw * gw;
    float ax = 0.f, ay = 0.f, az = 0.f, aw = 0.f;
#pragma unroll
    for (int t = 0; t < 5; ++t) {
        float4 nv = *(const float4*)(emb + (size_t)nb[t] * D + lane * 4);
        ax += nv.x; ay += nv.y; az += nv.z; aw += nv.w;
    }
    ax *= 0.2f; ay *= 0.2f; az *= 0.2f; aw *= 0.2f;
    float lx = e.x - ax, ly = e.y - ay, lz = e.z - az, lw = e.w - aw;
    float ld = lx * lx + ly * ly + lz * lz + lw * lw;
#pragma unroll
    for (int mk = 32; mk >= 1; mk >>= 1) {
        gd += __shfl_xor(gd, mk);
        ld += __shfl_xor(ld, mk);
    }
    if (lane == 0) {
        float sqv = ws[WS_SQ + row];
        float mn = ws[WS_MAXN];   // float bits via uint atomicMax (norms >= 0)
        float ent = logf(ll) - tt / ll;
        out[row] = sqv - pt / (dg + EPSF);
        out[N + row] = (dg > 0.f) ? ent : 0.f;
        out[2 * N + row] = 0.6f * sqrtf(gd) + 0.4f * sqrtf(ld);
        out[3 * N + row] = 0.5f * (dg / (8191.0f + EPSF)) + 0.5f * (sqrtf(sqv) / (mn + EPSF));
    }
}

extern "C" void kernel_launch(void* const* d_in, const int* in_sizes, int n_in,
                              void* d_out, int out_size, void* d_ws, size_t ws_size,
                              hipStream_t stream) {
    const float* emb = (const float*)d_in[0];
    const float* adj = (const float*)d_in[1];
    float* out = (float*)d_out;
    float* ws = (float*)d_ws;
    unsigned short* ebf = (unsigned short*)(ws + WS_EBF);

    hipMemsetAsync(ws + WS_MAXN, 0, 4, stream);
    k_prep<<<2304, 256, 0, stream>>>(emb, ws, ebf);
    k_colred<<<1, 256, 0, stream>>>(ws);
    k_main<<<1024, 256, 0, stream>>>(adj, ebf, ws, ws + WS_P0, (int*)(ws + WS_TIX));
    k_final<<<N / 4, 256, 0, stream>>>(emb, ws, (const int*)(ws + WS_TIX), out);
}

// Round 9
// 202.106 us; speedup vs baseline: 1.5749x; 1.5749x over previous
//
#include <hip/hip_runtime.h>
#include <math.h>

#define N 8192
#define D 256
#define EPSF 1e-8f
#define NJS 4            // j-splits
#define ROWS 32          // out-rows per block
#define JSPAN 2048       // j-cols per block
#define NU 64            // units per block: 16 chunks x 4 K-slices

// ws float offsets
#define WS_SQ    0
#define WS_RINV  (N)
#define WS_GMEAN (2*N)
#define WS_MAXN  (2*N+256)
#define WS_COLP  (2*N+512)              // [65536]
#define WS_P0    (2*N+512+65536)        // deg[4N] pot[4N] sl[4N] st[4N] tv[20N] = 36N
#define WS_TIX   (WS_P0+36*N)           // [20N] ints
#define WS_EBF   (WS_TIX+20*N)          // [2M ushort] bf16 emb (4MB)

typedef __attribute__((ext_vector_type(8))) short bf16x8;
typedef __attribute__((ext_vector_type(4))) float f32x4;

__device__ __forceinline__ unsigned short f2bf(float f) {
    unsigned u = __float_as_uint(f);
    u += 0x7fffu + ((u >> 16) & 1u);
    return (unsigned short)(u >> 16);
}

#define INS5(TV, TI, dpv, jv) do {                                              \
    if ((dpv) < (TV)[4]) {                                                      \
      bool _b3 = (dpv) < (TV)[3], _b2 = (dpv) < (TV)[2];                        \
      bool _b1 = (dpv) < (TV)[1], _b0 = (dpv) < (TV)[0];                        \
      (TV)[4] = _b3 ? (TV)[3] : (dpv); (TI)[4] = _b3 ? (TI)[3] : (jv);          \
      (TV)[3] = _b3 ? (_b2 ? (TV)[2] : (dpv)) : (TV)[3];                        \
      (TI)[3] = _b3 ? (_b2 ? (TI)[2] : (jv))  : (TI)[3];                        \
      (TV)[2] = _b2 ? (_b1 ? (TV)[1] : (dpv)) : (TV)[2];                        \
      (TI)[2] = _b2 ? (_b1 ? (TI)[1] : (jv))  : (TI)[2];                        \
      (TV)[1] = _b1 ? (_b0 ? (TV)[0] : (dpv)) : (TV)[1];                        \
      (TI)[1] = _b1 ? (_b0 ? (TI)[0] : (jv))  : (TI)[1];                        \
      (TV)[0] = _b0 ? (dpv) : (TV)[0]; (TI)[0] = _b0 ? (jv) : (TI)[0];          \
    }                                                                           \
  } while (0)

__global__ void k_prep(const float* __restrict__ emb, float* __restrict__ ws,
                       unsigned short* __restrict__ ebf) {
    if (blockIdx.x < 2048) {
        int row = blockIdx.x * 4 + (threadIdx.x >> 6);
        int lane = threadIdx.x & 63;
        float4 v = *(const float4*)(emb + (size_t)row * D + lane * 4);
        ushort4 b;
        b.x = f2bf(v.x); b.y = f2bf(v.y); b.z = f2bf(v.z); b.w = f2bf(v.w);
        *(ushort4*)(ebf + (size_t)row * D + lane * 4) = b;
        float s = v.x * v.x + v.y * v.y + v.z * v.z + v.w * v.w;
#pragma unroll
        for (int mk = 32; mk >= 1; mk >>= 1) s += __shfl_xor(s, mk);
        if (lane == 0) {
            ws[WS_SQ + row] = s;
            ws[WS_RINV + row] = 1.0f / fmaxf(sqrtf(s), 1e-12f);
        }
    } else {
        int d = threadIdx.x;
        int b = blockIdx.x - 2048;
        float s = 0.f;
        for (int r = b * 32; r < b * 32 + 32; ++r) s += emb[(size_t)r * D + d];
        ws[WS_COLP + b * 256 + d] = s;
    }
}

// gmean + maxnorm (no atomics, no memset -- R8 showed that path costs ~90us)
__global__ void k_colred(float* __restrict__ ws) {
    __shared__ float red[256];
    int d = threadIdx.x;
    float s = 0.f;
    for (int b = 0; b < 256; ++b) s += ws[WS_COLP + b * 256 + d];
    ws[WS_GMEAN + d] = s * (1.0f / N);
    float mx = 0.f;
    for (int i = d; i < N; i += 256) mx = fmaxf(mx, ws[WS_SQ + i]);
    red[d] = mx;
    __syncthreads();
#pragma unroll
    for (int st2 = 128; st2 >= 1; st2 >>= 1) {
        if (d < st2) red[d] = fmaxf(red[d], red[d + st2]);
        __syncthreads();
    }
    if (d == 0) ws[WS_MAXN] = sqrtf(red[0]);
}

// Stage unit U's [128 j][64 K] tile slab: wave w stages ONLY its own 32 rows
// (the same rows it later reads -> no cross-wave LDS dependency, no barriers).
// global_load_lds: linear LDS dest, PRE-SWIZZLED global src (16B groups,
// stored[row][c] = logical[row][c ^ (row&7)]).
#define STAGE(PTR, U) do {                                                      \
    const int _u = (U);                                                         \
    const int _cc2 = _u >> 2, _k0 = (_u & 3) << 6;                              \
    const size_t _rb = (size_t)(j0 + _cc2 * 128 + (w << 5) + srow) * D + _k0 + (sc << 3); \
    _Pragma("unroll")                                                           \
    for (int q = 0; q < 4; ++q) {                                               \
      __builtin_amdgcn_global_load_lds(                                         \
        (const __attribute__((address_space(1))) void*)(ebf + _rb + (size_t)(q << 3) * D), \
        (__attribute__((address_space(3))) void*)&(PTR)[((w << 5) + (q << 3)) * 64], \
        16, 0, 0);                                                              \
    } } while (0)

// counted vmcnt (T4): never drain to 0 in the main loop
#define VMW(NLIT) do {                                                          \
    asm volatile("s_waitcnt vmcnt(" #NLIT ")" ::: "memory");                    \
    __builtin_amdgcn_sched_barrier(0);                                          \
  } while (0)

#define SBAR() __builtin_amdgcn_sched_barrier(0)

// compute unit at buffer PTR with compile-time h = H (bfr K-index base)
#define COMP(PTR, H) do {                                                       \
    _Pragma("unroll")                                                           \
    for (int ksl = 0; ksl < 2; ++ksl) {                                         \
      const int pg = ((ksl << 2) + g) ^ (lid & 7);                              \
      bf16x8 afr[2];                                                            \
      _Pragma("unroll")                                                         \
      for (int mf = 0; mf < 2; ++mf)                                            \
        afr[mf] = *(const bf16x8*)&(PTR)[((w << 5) + (mf << 4) + lid) * 64 + (pg << 3)]; \
      _Pragma("unroll")                                                         \
      for (int nf = 0; nf < 2; ++nf)                                            \
        _Pragma("unroll")                                                       \
        for (int mf = 0; mf < 2; ++mf)                                          \
          acc[nf][mf] = __builtin_amdgcn_mfma_f32_16x16x32_bf16(                \
              afr[mf], bfr[nf][(H) * 2 + ksl], acc[nf][mf], 0, 0, 0);           \
    } } while (0)

// Block = 32 out-rows x 2048 j; 4 waves share out-rows, each wave owns a 32-j
// quadrant and runs a PRIVATE zero-barrier pipeline: 3 LDS buffers, staging
// distance 2, counted vmcnt 12/12/8/8 per quarter-chunk. Barriers only at the
// final cross-wave merge.
__global__ __launch_bounds__(256) void k_main(
    const float* __restrict__ adj,
    const unsigned short* __restrict__ ebf,
    const float* __restrict__ ws,
    float* __restrict__ pout,
    int* __restrict__ tixp)
{
    __shared__ unsigned short tile[3][128 * 64];   // 3 x 16KB

    const int tid = threadIdx.x;
    const int w = tid >> 6;
    const int l = tid & 63;
    const int lid = l & 15;
    const int g = l >> 4;
    const int srow = l >> 3;              // staging: row-in-slab 0..7
    const int sc = (l & 7) ^ srow;        // staging: pre-swizzled 16B group
    const int panel = blockIdx.x >> 2;    // 256 panels
    const int js = blockIdx.x & 3;
    const int row0 = panel * ROWS;
    const int j0 = js * JSPAN;

    const float* sq = ws + WS_SQ;
    const float* rinv = ws + WS_RINV;

    // persistent out-row fragments (same for all waves)
    bf16x8 bfr[2][8];
    float rvr[2];
    int r_[2];
#pragma unroll
    for (int nf = 0; nf < 2; ++nf) {
        int r = row0 + nf * 16 + lid;
        r_[nf] = r;
        rvr[nf] = rinv[r];
#pragma unroll
        for (int ks = 0; ks < 8; ++ks)
            bfr[nf][ks] = *(const bf16x8*)(ebf + (size_t)r * D + ks * 32 + g * 8);
    }

    float deg[2] = {0.f, 0.f}, pot[2] = {0.f, 0.f};
    float sl[2] = {0.f, 0.f}, st[2] = {0.f, 0.f};
    float tv[2][5]; int tix[2][5];
#pragma unroll
    for (int nf = 0; nf < 2; ++nf)
#pragma unroll
        for (int s2 = 0; s2 < 5; ++s2) { tv[nf][s2] = 1e30f; tix[nf][s2] = N; }

    f32x4 acc[2][2];
#pragma unroll
    for (int nf = 0; nf < 2; ++nf)
#pragma unroll
        for (int mf = 0; mf < 2; ++mf) acc[nf][mf] = (f32x4){0.f, 0.f, 0.f, 0.f};
    f32x4 advA[2][2], sqv[2], rvv[2];

    unsigned short* p0 = &tile[0][0];
    unsigned short* p1 = &tile[1][0];
    unsigned short* p2 = &tile[2][0];

    STAGE(p0, 0);
    STAGE(p1, 1);

#pragma unroll 1
    for (int cc = 0; cc < 16; ++cc) {
        const int u0 = cc << 2;
        const int jj = j0 + cc * 128 + (w << 5);

        // ---- h0: adj prefetch (consumed at h3), stage u0+2, compute unit u0
#pragma unroll
        for (int nf = 0; nf < 2; ++nf)
#pragma unroll
            for (int mf = 0; mf < 2; ++mf)
                advA[nf][mf] = __builtin_nontemporal_load(
                    (const f32x4*)(adj + (size_t)r_[nf] * N + jj + mf * 16 + g * 4));
        STAGE(p2, (u0 + 2) & 63);
        VMW(12);                    // outstanding: [s(u0),s(u0+1),adj,s(u0+2)] -> drain s(u0)
        COMP(p0, 0);

        // ---- h1: j-side stats, stage u0+3 (into p0, just read), compute u0+1
#pragma unroll
        for (int mf = 0; mf < 2; ++mf) {
            sqv[mf] = *(const f32x4*)(sq + jj + mf * 16 + g * 4);
            rvv[mf] = *(const f32x4*)(rinv + jj + mf * 16 + g * 4);
        }
        SBAR();                     // WAR fence: p0 reads must not sink below restage
        STAGE(p0, (u0 + 3) & 63);
        VMW(12);                    // [s(u0+1),adj,s(u0+2),s(u0+3)] -> drain s(u0+1)
        COMP(p1, 1);

        // ---- h2: stage u0+4 (into p1, just read), compute u0+2
        SBAR();
        STAGE(p1, (u0 + 4) & 63);
        VMW(8);                     // [adj,s(u0+2),s(u0+3),s(u0+4)] -> drain adj,s(u0+2)
        COMP(p2, 2);

        // ---- h3: stage u0+5 (into p2, just read), compute u0+3, epilogue
        SBAR();
        STAGE(p2, (u0 + 5) & 63);
        VMW(8);                     // [s(u0+3),s(u0+4),s(u0+5)] -> drain s(u0+3)
        COMP(p0, 3);
#pragma unroll
        for (int nf = 0; nf < 2; ++nf) {
#pragma unroll
            for (int mf = 0; mf < 2; ++mf) {
#pragma unroll
                for (int e = 0; e < 4; ++e) {
                    const float gv = acc[nf][mf][e];
                    const float a = advA[nf][mf][e];
                    const int j = jj + mf * 16 + g * 4 + e;
                    deg[nf] += a;
                    pot[nf] = fmaf(a, gv, pot[nf]);
                    const float s = (gv * rvr[nf]) * (rvv[mf][e] * a);
                    const float ex = __expf(s);
                    sl[nf] += ex;
                    st[nf] = fmaf(ex, s, st[nf]);
                    float dp = fmaf(-2.f, gv, sqv[mf][e]);
                    dp = (j == r_[nf]) ? 1e30f : dp;
                    INS5(tv[nf], tix[nf], dp, j);
                }
                acc[nf][mf] = (f32x4){0.f, 0.f, 0.f, 0.f};
            }
        }

        // rotate buffers: next chunk's units u0+4..u0+7 live in p1,p2,p0,p1...
        unsigned short* tmp = p0; p0 = p1; p1 = p2; p2 = tmp;
    }

    // reduce across g-lanes (xor 16, 32) sharing each out-row
#pragma unroll
    for (int nf = 0; nf < 2; ++nf) {
#pragma unroll
        for (int mk = 16; mk <= 32; mk <<= 1) {
            deg[nf] += __shfl_xor(deg[nf], mk);
            pot[nf] += __shfl_xor(pot[nf], mk);
            sl[nf] += __shfl_xor(sl[nf], mk);
            st[nf] += __shfl_xor(st[nf], mk);
            float od[5]; int oi[5];
#pragma unroll
            for (int s2 = 0; s2 < 5; ++s2) {
                od[s2] = __shfl_xor(tv[nf][s2], mk);
                oi[s2] = __shfl_xor(tix[nf][s2], mk);
            }
#pragma unroll
            for (int s2 = 0; s2 < 5; ++s2) INS5(tv[nf], tix[nf], od[s2], oi[s2]);
        }
    }

    // cross-wave merge via LDS overlay on tile[0] (all waves done with tiles
    // after the barrier below)
    __syncthreads();
    float* lds_s  = (float*)&tile[0][0];           // [4][32][4]
    float* lds_tv = lds_s + 4 * 32 * 4;            // [4][32][5]
    int*   lds_ti = (int*)(lds_tv + 4 * 32 * 5);   // [4][32][5]
#pragma unroll
    for (int nf = 0; nf < 2; ++nf) {
        if (g == 0) {
            int lr = nf * 16 + lid;
            lds_s[(w * 32 + lr) * 4 + 0] = deg[nf];
            lds_s[(w * 32 + lr) * 4 + 1] = pot[nf];
            lds_s[(w * 32 + lr) * 4 + 2] = sl[nf];
            lds_s[(w * 32 + lr) * 4 + 3] = st[nf];
#pragma unroll
            for (int s2 = 0; s2 < 5; ++s2) {
                lds_tv[(w * 32 + lr) * 5 + s2] = tv[nf][s2];
                lds_ti[(w * 32 + lr) * 5 + s2] = tix[nf][s2];
            }
        }
    }
    __syncthreads();

    if (tid < 32) {
        float dg = 0.f, pt = 0.f, ll = 0.f, tt = 0.f;
#pragma unroll
        for (int w2 = 0; w2 < 4; ++w2) {
            dg += lds_s[(w2 * 32 + tid) * 4 + 0];
            pt += lds_s[(w2 * 32 + tid) * 4 + 1];
            ll += lds_s[(w2 * 32 + tid) * 4 + 2];
            tt += lds_s[(w2 * 32 + tid) * 4 + 3];
        }
        float mtv[5]; int mti[5];
#pragma unroll
        for (int s2 = 0; s2 < 5; ++s2) {
            mtv[s2] = lds_tv[tid * 5 + s2];
            mti[s2] = lds_ti[tid * 5 + s2];
        }
#pragma unroll
        for (int w2 = 1; w2 < 4; ++w2)
#pragma unroll
            for (int s2 = 0; s2 < 5; ++s2)
                INS5(mtv, mti, lds_tv[(w2 * 32 + tid) * 5 + s2], lds_ti[(w2 * 32 + tid) * 5 + s2]);
        const int slot = js * N + row0 + tid;
        pout[slot] = dg;
        pout[4 * N + slot] = pt;
        pout[8 * N + slot] = ll;
        pout[12 * N + slot] = tt;
#pragma unroll
        for (int s2 = 0; s2 < 5; ++s2) {
            pout[16 * N + slot * 5 + s2] = mtv[s2];
            tixp[slot * 5 + s2] = mti[s2];
        }
    }
}

__global__ void k_final(const float* __restrict__ emb, const float* __restrict__ ws,
                        const int* __restrict__ tixp, float* __restrict__ out) {
    int row = blockIdx.x * 4 + (threadIdx.x >> 6);
    int lane = threadIdx.x & 63;
    const float* p0 = ws + WS_P0;

    float dg = 0.f, pt = 0.f, ll = 0.f, tt = 0.f;
#pragma unroll
    for (int js = 0; js < NJS; ++js) {
        int slot = js * N + row;
        dg += p0[slot]; pt += p0[4 * N + slot];
        ll += p0[8 * N + slot]; tt += p0[12 * N + slot];
    }

    float cd[20]; int ci[20];
#pragma unroll
    for (int js = 0; js < NJS; ++js)
#pragma unroll
        for (int s = 0; s < 5; ++s) {
            int slot = js * N + row;
            cd[js * 5 + s] = p0[16 * N + slot * 5 + s];
            ci[js * 5 + s] = tixp[slot * 5 + s];
        }
    int nb[5];
    unsigned picked = 0;
#pragma unroll
    for (int sel = 0; sel < 5; ++sel) {
        float best = 1e31f; int bi = 0, bq = 0;
#pragma unroll
        for (int q = 0; q < 20; ++q) {
            bool ok = (((picked >> q) & 1u) == 0u) && (cd[q] < best);
            best = ok ? cd[q] : best;
            bi = ok ? ci[q] : bi;
            bq = ok ? q : bq;
        }
        picked |= (1u << bq);
        nb[sel] = bi;
    }

    float4 e = *(const float4*)(emb + (size_t)row * D + lane * 4);
    float4 gm = *(const float4*)(ws + WS_GMEAN + lane * 4);
    float gx = e.x - gm.x, gy = e.y - gm.y, gz = e.z - gm.z, gw = e.w - gm.w;
    float gd = gx * gx + gy * gy + gz * gz + gw * gw;
    float ax = 0.f, ay = 0.f, az = 0.f, aw = 0.f;
#pragma unroll
    for (int t = 0; t < 5; ++t) {
        float4 nv = *(const float4*)(emb + (size_t)nb[t] * D + lane * 4);
        ax += nv.x; ay += nv.y; az += nv.z; aw += nv.w;
    }
    ax *= 0.2f; ay *= 0.2f; az *= 0.2f; aw *= 0.2f;
    float lx = e.x - ax, ly = e.y - ay, lz = e.z - az, lw = e.w - aw;
    float ld = lx * lx + ly * ly + lz * lz + lw * lw;
#pragma unroll
    for (int mk = 32; mk >= 1; mk >>= 1) {
        gd += __shfl_xor(gd, mk);
        ld += __shfl_xor(ld, mk);
    }
    if (lane == 0) {
        float sqv = ws[WS_SQ + row];
        float mn = ws[WS_MAXN];
        float ent = logf(ll) - tt / ll;
        out[row] = sqv - pt / (dg + EPSF);
        out[N + row] = (dg > 0.f) ? ent : 0.f;
        out[2 * N + row] = 0.6f * sqrtf(gd) + 0.4f * sqrtf(ld);
        out[3 * N + row] = 0.5f * (dg / (8191.0f + EPSF)) + 0.5f * (sqrtf(sqv) / (mn + EPSF));
    }
}

extern "C" void kernel_launch(void* const* d_in, const int* in_sizes, int n_in,
                              void* d_out, int out_size, void* d_ws, size_t ws_size,
                              hipStream_t stream) {
    const float* emb = (const float*)d_in[0];
    const float* adj = (const float*)d_in[1];
    float* out = (float*)d_out;
    float* ws = (float*)d_ws;
    unsigned short* ebf = (unsigned short*)(ws + WS_EBF);

    k_prep<<<2304, 256, 0, stream>>>(emb, ws, ebf);
    k_colred<<<1, 256, 0, stream>>>(ws);
    k_main<<<1024, 256, 0, stream>>>(adj, ebf, ws, ws + WS_P0, (int*)(ws + WS_TIX));
    k_final<<<N / 4, 256, 0, stream>>>(emb, ws, (const int*)(ws + WS_TIX), out);
}

// Round 10
// 157.220 us; speedup vs baseline: 2.0245x; 1.2855x over previous
//
#include <hip/hip_runtime.h>
#include <math.h>

#define N 8192
#define D 256
#define EPSF 1e-8f
#define NJS 2            // j-splits
#define ROWS 32          // out-rows per block
#define JSPAN 4096       // j-cols per block
#define NCH 32           // 128-j chunks per block
#define NU 128           // units (chunk x 4 K-slices)

// ws float offsets (layout kept compatible with prior rounds)
#define WS_SQ    0
#define WS_RINV  (N)
#define WS_GMEAN (2*N)
#define WS_MAXN  (2*N+256)
#define WS_COLP  (2*N+512)              // [65536]
#define WS_P0    (2*N+512+65536)        // deg[2N] pot[2N] sl[2N] st[2N] keys[10N]
#define WS_EBF   (WS_P0+56*N)           // [2M ushort] bf16 emb (4MB)

typedef __attribute__((ext_vector_type(8))) short bf16x8;
typedef __attribute__((ext_vector_type(4))) float f32x4;

__device__ __forceinline__ unsigned short f2bf(float f) {
    unsigned u = __float_as_uint(f);
    u += 0x7fffu + ((u >> 16) & 1u);
    return (unsigned short)(u >> 16);
}

#if __has_builtin(__builtin_amdgcn_fmed3f)
#define MED3(a,b,c) __builtin_amdgcn_fmed3f((a),(b),(c))
#else
#define MED3(a,b,c) fmaxf(fminf((a),(b)), fminf(fmaxf((a),(b)),(c)))
#endif

// branchless sorted-5 insert on packed keys (val high bits | index low 13)
#define PINS(T, x) do {                                                         \
    float _x = (x);                                                             \
    float _n0 = fminf((T)[0], _x);                                              \
    float _n1 = MED3((T)[0], (T)[1], _x);                                       \
    float _n2 = MED3((T)[1], (T)[2], _x);                                       \
    float _n3 = MED3((T)[2], (T)[3], _x);                                       \
    float _n4 = MED3((T)[3], (T)[4], _x);                                       \
    (T)[0]=_n0; (T)[1]=_n1; (T)[2]=_n2; (T)[3]=_n3; (T)[4]=_n4;                 \
  } while (0)

__global__ void k_prep(const float* __restrict__ emb, float* __restrict__ ws,
                       unsigned short* __restrict__ ebf) {
    if (blockIdx.x < 2048) {
        int row = blockIdx.x * 4 + (threadIdx.x >> 6);
        int lane = threadIdx.x & 63;
        float4 v = *(const float4*)(emb + (size_t)row * D + lane * 4);
        ushort4 b;
        b.x = f2bf(v.x); b.y = f2bf(v.y); b.z = f2bf(v.z); b.w = f2bf(v.w);
        *(ushort4*)(ebf + (size_t)row * D + lane * 4) = b;
        float s = v.x * v.x + v.y * v.y + v.z * v.z + v.w * v.w;
#pragma unroll
        for (int mk = 32; mk >= 1; mk >>= 1) s += __shfl_xor(s, mk);
        if (lane == 0) {
            ws[WS_SQ + row] = s;
            ws[WS_RINV + row] = 1.0f / fmaxf(sqrtf(s), 1e-12f);
        }
    } else {
        int d = threadIdx.x;
        int b = blockIdx.x - 2048;
        float s = 0.f;
        for (int r = b * 32; r < b * 32 + 32; ++r) s += emb[(size_t)r * D + d];
        ws[WS_COLP + b * 256 + d] = s;
    }
}

__global__ void k_colred(float* __restrict__ ws) {
    __shared__ float red[256];
    int d = threadIdx.x;
    float s = 0.f;
    for (int b = 0; b < 256; ++b) s += ws[WS_COLP + b * 256 + d];
    ws[WS_GMEAN + d] = s * (1.0f / N);
    float mx = 0.f;
    for (int i = d; i < N; i += 256) mx = fmaxf(mx, ws[WS_SQ + i]);
    red[d] = mx;
    __syncthreads();
#pragma unroll
    for (int st2 = 128; st2 >= 1; st2 >>= 1) {
        if (d < st2) red[d] = fmaxf(red[d], red[d + st2]);
        __syncthreads();
    }
    if (d == 0) ws[WS_MAXN] = sqrtf(red[0]);
}

// Stage unit U: wave w stages ONLY its own 32 rows (same rows it reads ->
// no cross-wave dependency, no barriers). Linear LDS dest, pre-swizzled src.
#define STAGE(PTR, U) do {                                                      \
    const int _u = (U);                                                         \
    const int _cc2 = _u >> 2, _k0 = (_u & 3) << 6;                              \
    const size_t _rb = (size_t)(j0 + _cc2 * 128 + (w << 5) + srow) * D + _k0 + (sc << 3); \
    _Pragma("unroll")                                                           \
    for (int q = 0; q < 4; ++q) {                                               \
      __builtin_amdgcn_global_load_lds(                                         \
        (const __attribute__((address_space(1))) void*)(ebf + _rb + (size_t)(q << 3) * D), \
        (__attribute__((address_space(3))) void*)&(PTR)[((w << 5) + (q << 3)) * 64], \
        16, 0, 0);                                                              \
    } } while (0)

#define VMW(NLIT) do {                                                          \
    asm volatile("s_waitcnt vmcnt(" #NLIT ")" ::: "memory");                    \
    __builtin_amdgcn_sched_barrier(0);                                          \
  } while (0)

#define SBAR() __builtin_amdgcn_sched_barrier(0)

#define COMP(PTR, H) do {                                                       \
    _Pragma("unroll")                                                           \
    for (int ksl = 0; ksl < 2; ++ksl) {                                         \
      const int pg = ((ksl << 2) + g) ^ (lid & 7);                              \
      bf16x8 afr[2];                                                            \
      _Pragma("unroll")                                                         \
      for (int mf = 0; mf < 2; ++mf)                                            \
        afr[mf] = *(const bf16x8*)&(PTR)[((w << 5) + (mf << 4) + lid) * 64 + (pg << 3)]; \
      _Pragma("unroll")                                                         \
      for (int nf = 0; nf < 2; ++nf)                                            \
        _Pragma("unroll")                                                       \
        for (int mf = 0; mf < 2; ++mf)                                          \
          acc[nf][mf] = __builtin_amdgcn_mfma_f32_16x16x32_bf16(                \
              afr[mf], bfr[nf][(H) * 2 + ksl], acc[nf][mf], 0, 0, 0);           \
    } } while (0)

// Block = 32 out-rows x 4096 j; 4 waves share out-rows, each owns a 32-j
// quadrant per chunk. Zero-barrier private pipelines, 3 LDS buffers,
// counted vmcnt 12/16/16/8 (adj gets a 3-unit window; never forced early).
__global__ __launch_bounds__(256) void k_main(
    const float* __restrict__ adj,
    const unsigned short* __restrict__ ebf,
    const float* __restrict__ ws,
    float* __restrict__ pout)
{
    __shared__ unsigned short tile[3][128 * 64];   // 3 x 16KB

    const int tid = threadIdx.x;
    const int w = tid >> 6;
    const int l = tid & 63;
    const int lid = l & 15;
    const int g = l >> 4;
    const int srow = l >> 3;
    const int sc = (l & 7) ^ srow;
    const int panel = blockIdx.x >> 1;    // 256 panels
    const int js = blockIdx.x & 1;
    const int row0 = panel * ROWS;
    const int j0 = js * JSPAN;

    const float* sq = ws + WS_SQ;
    const float* rinv = ws + WS_RINV;

    bf16x8 bfr[2][8];
    float rvr[2];
    int r_[2];
#pragma unroll
    for (int nf = 0; nf < 2; ++nf) {
        int r = row0 + nf * 16 + lid;
        r_[nf] = r;
        rvr[nf] = rinv[r];
#pragma unroll
        for (int ks = 0; ks < 8; ++ks)
            bfr[nf][ks] = *(const bf16x8*)(ebf + (size_t)r * D + ks * 32 + g * 8);
    }

    float deg[2] = {0.f, 0.f}, pot[2] = {0.f, 0.f};
    float sl[2] = {0.f, 0.f}, st[2] = {0.f, 0.f};
    float tv[2][5];
#pragma unroll
    for (int nf = 0; nf < 2; ++nf)
#pragma unroll
        for (int s2 = 0; s2 < 5; ++s2) tv[nf][s2] = 1e30f;

    f32x4 acc[2][2];
#pragma unroll
    for (int nf = 0; nf < 2; ++nf)
#pragma unroll
        for (int mf = 0; mf < 2; ++mf) acc[nf][mf] = (f32x4){0.f, 0.f, 0.f, 0.f};
    f32x4 advA[2][2], sqv[2], rvv[2];

    unsigned short* p0 = &tile[0][0];
    unsigned short* p1 = &tile[1][0];
    unsigned short* p2 = &tile[2][0];

    STAGE(p0, 0);
    STAGE(p1, 1);

#pragma unroll 1
    for (int cc = 0; cc < NCH; ++cc) {
        const int u0 = cc << 2;
        const int jj = j0 + cc * 128 + (w << 5);

        // h0: stage u0+2, THEN adj issue (stays newer than S(u0+2) in FIFO ->
        // survives until h3's wait: ~3-unit window), compute u0
        STAGE(p2, (u0 + 2) & (NU - 1));
#pragma unroll
        for (int nf = 0; nf < 2; ++nf)
#pragma unroll
            for (int mf = 0; mf < 2; ++mf)
                advA[nf][mf] = __builtin_nontemporal_load(
                    (const f32x4*)(adj + (size_t)r_[nf] * N + jj + mf * 16 + g * 4));
        VMW(12);                    // [S(u0),S(u0+1),S(u0+2),A] -> drain S(u0)
        COMP(p0, 0);

        // h1: j-stats issue, stage u0+3 (into p0, just read), compute u0+1
#pragma unroll
        for (int mf = 0; mf < 2; ++mf) {
            sqv[mf] = *(const f32x4*)(sq + jj + mf * 16 + g * 4);
            rvv[mf] = *(const f32x4*)(rinv + jj + mf * 16 + g * 4);
        }
        SBAR();
        STAGE(p0, (u0 + 3) & (NU - 1));
        VMW(16);                    // drain S(u0+1); keep S(u0+2),A,Q,S(u0+3)
        COMP(p1, 1);

        // h2: stage u0+4 (into p1), compute u0+2
        SBAR();
        STAGE(p1, (u0 + 4) & (NU - 1));
        VMW(16);                    // drain S(u0+2); keep A,Q,S(u0+3),S(u0+4)
        COMP(p2, 2);

        // h3: stage u0+5 (into p2), compute u0+3, epilogue (A,Q now drained)
        SBAR();
        STAGE(p2, (u0 + 5) & (NU - 1));
        VMW(8);                     // drain A,Q,S(u0+3); keep S(u0+4),S(u0+5)
        COMP(p0, 3);
#pragma unroll
        for (int nf = 0; nf < 2; ++nf) {
#pragma unroll
            for (int mf = 0; mf < 2; ++mf) {
#pragma unroll
                for (int e = 0; e < 4; ++e) {
                    const float gv = acc[nf][mf][e];
                    const float a = advA[nf][mf][e];
                    const int j = jj + mf * 16 + g * 4 + e;
                    deg[nf] += a;
                    pot[nf] = fmaf(a, gv, pot[nf]);
                    const float s = (gv * rvr[nf]) * (rvv[mf][e] * a);
                    const float ex = __expf(s);
                    sl[nf] += ex;
                    st[nf] = fmaf(ex, s, st[nf]);
                    float dp = fmaf(-2.f, gv, sqv[mf][e]);
                    dp = (j == r_[nf]) ? 1e30f : dp;
                    const float key = __uint_as_float(
                        (__float_as_uint(dp) & 0xFFFFE000u) | (unsigned)j);
                    PINS(tv[nf], key);
                }
                acc[nf][mf] = (f32x4){0.f, 0.f, 0.f, 0.f};
            }
        }

        unsigned short* tmp = p0; p0 = p1; p1 = p2; p2 = tmp;
    }

    // reduce across g-lanes (xor 16, 32) sharing each out-row
#pragma unroll
    for (int nf = 0; nf < 2; ++nf) {
#pragma unroll
        for (int mk = 16; mk <= 32; mk <<= 1) {
            deg[nf] += __shfl_xor(deg[nf], mk);
            pot[nf] += __shfl_xor(pot[nf], mk);
            sl[nf] += __shfl_xor(sl[nf], mk);
            st[nf] += __shfl_xor(st[nf], mk);
            float ok[5];
#pragma unroll
            for (int s2 = 0; s2 < 5; ++s2) ok[s2] = __shfl_xor(tv[nf][s2], mk);
#pragma unroll
            for (int s2 = 0; s2 < 5; ++s2) PINS(tv[nf], ok[s2]);
        }
    }

    // cross-wave merge via LDS overlay on tile[0]
    __syncthreads();
    float* lds_s = (float*)&tile[0][0];            // [4][32][4]
    float* lds_k = lds_s + 4 * 32 * 4;             // [4][32][5]
#pragma unroll
    for (int nf = 0; nf < 2; ++nf) {
        if (g == 0) {
            int lr = nf * 16 + lid;
            lds_s[(w * 32 + lr) * 4 + 0] = deg[nf];
            lds_s[(w * 32 + lr) * 4 + 1] = pot[nf];
            lds_s[(w * 32 + lr) * 4 + 2] = sl[nf];
            lds_s[(w * 32 + lr) * 4 + 3] = st[nf];
#pragma unroll
            for (int s2 = 0; s2 < 5; ++s2)
                lds_k[(w * 32 + lr) * 5 + s2] = tv[nf][s2];
        }
    }
    __syncthreads();

    if (tid < 32) {
        float dg = 0.f, pt = 0.f, ll = 0.f, tt = 0.f;
#pragma unroll
        for (int w2 = 0; w2 < 4; ++w2) {
            dg += lds_s[(w2 * 32 + tid) * 4 + 0];
            pt += lds_s[(w2 * 32 + tid) * 4 + 1];
            ll += lds_s[(w2 * 32 + tid) * 4 + 2];
            tt += lds_s[(w2 * 32 + tid) * 4 + 3];
        }
        float mk5[5];
#pragma unroll
        for (int s2 = 0; s2 < 5; ++s2) mk5[s2] = lds_k[tid * 5 + s2];
#pragma unroll
        for (int w2 = 1; w2 < 4; ++w2)
#pragma unroll
            for (int s2 = 0; s2 < 5; ++s2)
                PINS(mk5, lds_k[(w2 * 32 + tid) * 5 + s2]);
        const int slot = js * N + row0 + tid;
        pout[slot] = dg;
        pout[2 * N + slot] = pt;
        pout[4 * N + slot] = ll;
        pout[6 * N + slot] = tt;
#pragma unroll
        for (int s2 = 0; s2 < 5; ++s2)
            pout[8 * N + slot * 5 + s2] = mk5[s2];
    }
}

__global__ void k_final(const float* __restrict__ emb, const float* __restrict__ ws,
                        float* __restrict__ out) {
    int row = blockIdx.x * 4 + (threadIdx.x >> 6);
    int lane = threadIdx.x & 63;
    const float* p0 = ws + WS_P0;

    float dg = 0.f, pt = 0.f, ll = 0.f, tt = 0.f;
#pragma unroll
    for (int js = 0; js < NJS; ++js) {
        int slot = js * N + row;
        dg += p0[slot]; pt += p0[2 * N + slot];
        ll += p0[4 * N + slot]; tt += p0[6 * N + slot];
    }

    float keys[5];
#pragma unroll
    for (int s = 0; s < 5; ++s) keys[s] = p0[8 * N + (size_t)row * 5 + s];
#pragma unroll
    for (int s = 0; s < 5; ++s) PINS(keys, p0[8 * N + (size_t)(N + row) * 5 + s]);
    int nb[5];
#pragma unroll
    for (int t = 0; t < 5; ++t) nb[t] = (int)(__float_as_uint(keys[t]) & 0x1FFFu);

    float4 e = *(const float4*)(emb + (size_t)row * D + lane * 4);
    float4 gm = *(const float4*)(ws + WS_GMEAN + lane * 4);
    float gx = e.x - gm.x, gy = e.y - gm.y, gz = e.z - gm.z, gw = e.w - gm.w;
    float gd = gx * gx + gy * gy + gz * gz + gw * gw;
    float ax = 0.f, ay = 0.f, az = 0.f, aw = 0.f;
#pragma unroll
    for (int t = 0; t < 5; ++t) {
        float4 nv = *(const float4*)(emb + (size_t)nb[t] * D + lane * 4);
        ax += nv.x; ay += nv.y; az += nv.z; aw += nv.w;
    }
    ax *= 0.2f; ay *= 0.2f; az *= 0.2f; aw *= 0.2f;
    float lx = e.x - ax, ly = e.y - ay, lz = e.z - az, lw = e.w - aw;
    float ld = lx * lx + ly * ly + lz * lz + lw * lw;
#pragma unroll
    for (int mk = 32; mk >= 1; mk >>= 1) {
        gd += __shfl_xor(gd, mk);
        ld += __shfl_xor(ld, mk);
    }
    if (lane == 0) {
        float sqv = ws[WS_SQ + row];
        float mn = ws[WS_MAXN];
        float ent = logf(ll) - tt / ll;
        out[row] = sqv - pt / (dg + EPSF);
        out[N + row] = (dg > 0.f) ? ent : 0.f;
        out[2 * N + row] = 0.6f * sqrtf(gd) + 0.4f * sqrtf(ld);
        out[3 * N + row] = 0.5f * (dg / (8191.0f + EPSF)) + 0.5f * (sqrtf(sqv) / (mn + EPSF));
    }
}

extern "C" void kernel_launch(void* const* d_in, const int* in_sizes, int n_in,
                              void* d_out, int out_size, void* d_ws, size_t ws_size,
                              hipStream_t stream) {
    const float* emb = (const float*)d_in[0];
    const float* adj = (const float*)d_in[1];
    float* out = (float*)d_out;
    float* ws = (float*)d_ws;
    unsigned short* ebf = (unsigned short*)(ws + WS_EBF);

    k_prep<<<2304, 256, 0, stream>>>(emb, ws, ebf);
    k_colred<<<1, 256, 0, stream>>>(ws);
    k_main<<<512, 256, 0, stream>>>(adj, ebf, ws, ws + WS_P0);
    k_final<<<N / 4, 256, 0, stream>>>(emb, ws, out);
}